// Round 1
// baseline (4298.843 us; speedup 1.0000x reference)
//
#include <hip/hip_runtime.h>

typedef unsigned short u16;
typedef unsigned int   u32;

#define DI __device__ __forceinline__

DI float b2f(u16 u){ union{u32 i; float f;} x; x.i = ((u32)u)<<16; return x.f; }
DI u16 f2bf(float f){ union{float f; u32 i;} x; x.f=f; u32 r = x.i + 0x7FFFu + ((x.i>>16)&1u); return (u16)(r>>16); }
DI float sigf(float x){ return 1.0f/(1.0f + __expf(-x)); }
DI float tanh_(float x){ return 1.0f - 2.0f/(__expf(2.0f*x)+1.0f); }
DI float dot4(float4 a, float4 b){ return a.x*b.x + a.y*b.y + a.z*b.z + a.w*b.w; }

// ---------------- conv1 (k=7,pad3) + BN1 + ReLU + maxpool2 ----------------
// x: [128][2048][8] f32  -> out: [128][128][1024] bf16  (layout [b][co][t'])
__global__ __launch_bounds__(256) void k_conv1(
    const float* __restrict__ x, const float* __restrict__ w,
    const float* __restrict__ cb, const float* __restrict__ bg, const float* __restrict__ bb,
    const float* __restrict__ bm, const float* __restrict__ bv, u16* __restrict__ out)
{
  __shared__ __align__(16) float xs[262*8];
  __shared__ __align__(16) float wl[128*7*8];   // [co][k][ci]
  __shared__ float As[128], Ss[128];
  const int tid = threadIdx.x;
  const int tc  = blockIdx.x;       // 8 chunks of 128 pooled positions
  const int b   = blockIdx.y;
  const int tau0 = tc*256;
  for(int f = tid; f < 262*8; f += 256){
    int tt = f >> 3;
    int ci = f & 7;
    int xg = tau0 - 3 + tt;
    float val = 0.f;
    if(xg >= 0 && xg < 2048) val = x[(b*2048 + xg)*8 + ci];
    xs[f] = val;
  }
  for(int d = tid; d < 128*7*8; d += 256){
    int co = d / 56; int r = d - co*56; int k = r >> 3; int ci = r & 7;
    wl[d] = w[(co*8 + ci)*7 + k];
  }
  if(tid < 128){
    float a = bg[tid] * rsqrtf(bv[tid] + 1e-5f);
    As[tid] = a;
    Ss[tid] = (cb[tid] - bm[tid])*a + bb[tid];
  }
  __syncthreads();
  const float4* xs4 = (const float4*)xs;
  const float4* wl4 = (const float4*)wl;
  for(int i = 0; i < 64; i++){
    int idx = i*256 + tid;
    int co = idx >> 7, p = idx & 127;
    float4 xa[8], xb[8];
    #pragma unroll
    for(int d=0; d<8; d++){ xa[d] = xs4[(2*p + d)*2]; xb[d] = xs4[(2*p + d)*2 + 1]; }
    float a0 = 0.f, a1 = 0.f;
    #pragma unroll
    for(int k=0;k<7;k++){
      float4 wa = wl4[(co*7+k)*2], wb = wl4[(co*7+k)*2+1];
      a0 += dot4(xa[k],   wa) + dot4(xb[k],   wb);
      a1 += dot4(xa[k+1], wa) + dot4(xb[k+1], wb);
    }
    float Ac = As[co], Sc = Ss[co];
    float y = fmaxf(fmaxf(a0*Ac+Sc, a1*Ac+Sc), 0.f);
    out[((b*128 + co)<<10) + tc*128 + p] = f2bf(y);
  }
}

// ---------------- conv2 (k=5,pad2) + BN2 + ReLU + maxpool2 ----------------
// in: [128][128][1024] bf16 -> seq: [512][128][256] bf16 (layout [t'][b][co])
__global__ __launch_bounds__(256) void k_conv2(
    const u16* __restrict__ cin, const float* __restrict__ w,
    const float* __restrict__ cb, const float* __restrict__ bg, const float* __restrict__ bb,
    const float* __restrict__ bm, const float* __restrict__ bv, u16* __restrict__ seq)
{
  __shared__ __align__(16) float xs[16*132];
  __shared__ __align__(16) float wl[64*16*8];   // [c][ci][k(pad8)]
  __shared__ float As[64], Ss[64];
  const int tid = threadIdx.x;
  const int tc  = blockIdx.x;    // 0..7  (64 pooled t' per chunk)
  const int cog = blockIdx.y;    // 0..3  (64 co per group)
  const int b   = blockIdx.z;
  const int co0 = cog*64;
  const int tau0 = tc*128;
  if(tid < 64){
    int co = co0 + tid;
    float a = bg[co] * rsqrtf(bv[co] + 1e-5f);
    As[tid] = a; Ss[tid] = (cb[co] - bm[co])*a + bb[co];
  }
  const int q  = tid & 15;       // t' group of 4
  const int cg = tid >> 4;       // co group of 4
  float acc[4][4][2];
  #pragma unroll
  for(int c=0;c<4;c++)
    #pragma unroll
    for(int tl=0;tl<4;tl++){ acc[c][tl][0]=0.f; acc[c][tl][1]=0.f; }
  for(int ci0 = 0; ci0 < 128; ci0 += 16){
    __syncthreads();
    for(int f = tid; f < 16*132; f += 256){
      int ci = f / 132, tt = f - ci*132;
      int tg = tau0 + tt - 2;
      float val = 0.f;
      if(tg >= 0 && tg < 1024) val = b2f(cin[((b*128 + ci0+ci)<<10) + tg]);
      xs[f] = val;
    }
    for(int f = tid; f < 64*16*5; f += 256){
      int c = f / 80; int r = f - c*80; int ci = r/5; int k = r - ci*5;
      wl[(c*16+ci)*8 + k] = w[((co0+c)*128 + ci0+ci)*5 + k];
    }
    __syncthreads();
    #pragma unroll 4
    for(int ci = 0; ci < 16; ci++){
      const float4* xr = (const float4*)&xs[ci*132 + 8*q];
      float4 x0 = xr[0], x1 = xr[1], x2 = xr[2];
      float xv[12];
      xv[0]=x0.x; xv[1]=x0.y; xv[2]=x0.z; xv[3]=x0.w;
      xv[4]=x1.x; xv[5]=x1.y; xv[6]=x1.z; xv[7]=x1.w;
      xv[8]=x2.x; xv[9]=x2.y; xv[10]=x2.z; xv[11]=x2.w;
      #pragma unroll
      for(int c=0;c<4;c++){
        const float* wp = &wl[((cg*4+c)*16 + ci)*8];
        float w0=wp[0], w1=wp[1], w2=wp[2], w3=wp[3], w4=wp[4];
        #pragma unroll
        for(int tl=0; tl<4; tl++){
          acc[c][tl][0] += xv[2*tl+0]*w0 + xv[2*tl+1]*w1 + xv[2*tl+2]*w2 + xv[2*tl+3]*w3 + xv[2*tl+4]*w4;
          acc[c][tl][1] += xv[2*tl+1]*w0 + xv[2*tl+2]*w1 + xv[2*tl+3]*w2 + xv[2*tl+4]*w3 + xv[2*tl+5]*w4;
        }
      }
    }
  }
  #pragma unroll
  for(int c=0;c<4;c++){
    float Ac = As[cg*4+c], Sc = Ss[cg*4+c];
    #pragma unroll
    for(int tl=0;tl<4;tl++){
      float y0 = acc[c][tl][0]*Ac + Sc;
      float y1 = acc[c][tl][1]*Ac + Sc;
      float y  = fmaxf(fmaxf(y0, y1), 0.f);
      int tp = tc*64 + q*4 + tl;
      seq[(tp*128 + b)*256 + co0 + cg*4 + c] = f2bf(y);
    }
  }
}

// ---------------- xp = LN(seq @ wih.T + bih)  (per direction) ----------------
// seq: [65536 rows][256] bf16 ; wih: [384][256] f32 ; out xp: [rows][384] bf16
__global__ __launch_bounds__(512) void k_xp(
    const u16* __restrict__ seq,
    const float* __restrict__ fw, const float* __restrict__ fbi, const float* __restrict__ fg, const float* __restrict__ fb,
    const float* __restrict__ bw, const float* __restrict__ bbi, const float* __restrict__ bg_, const float* __restrict__ bb_,
    u16* __restrict__ xpf, u16* __restrict__ xpb)
{
  __shared__ __align__(16) float sT[32*36];     // [k][r] pitch 36
  __shared__ __align__(16) float wT[32*386];    // [k][j] pitch 386
  const float *W, *BI, *LG, *LB; u16* out;
  if(blockIdx.y == 0){ W=fw; BI=fbi; LG=fg;  LB=fb;  out=xpf; }
  else               { W=bw; BI=bbi; LG=bg_; LB=bb_; out=xpb; }
  const int tid = threadIdx.x;
  const int row0 = blockIdx.x * 32;
  const int jg = tid & 63, rg = tid >> 6;       // wave rg owns rows rg*4..+3
  const int j0 = jg*6;
  float bi6[6], g6[6], b6[6];
  #pragma unroll
  for(int e=0;e<6;e++){ bi6[e]=BI[j0+e]; g6[e]=LG[j0+e]; b6[e]=LB[j0+e]; }
  float acc[4][6];
  #pragma unroll
  for(int r=0;r<4;r++)
    #pragma unroll
    for(int e=0;e<6;e++) acc[r][e]=0.f;
  for(int k0=0;k0<256;k0+=32){
    __syncthreads();
    {
      int r = tid >> 4; int kk = (tid & 15)*2;
      u32 pv = *(const u32*)&seq[(row0 + r)*256 + k0 + kk];
      sT[kk*36 + r]     = b2f((u16)(pv & 0xffffu));
      sT[(kk+1)*36 + r] = b2f((u16)(pv >> 16));
    }
    #pragma unroll
    for(int rep=0; rep<24; rep++){
      int flat = rep*512 + tid;                 // 0..12287 = 384*32
      int j = flat >> 5; int kk = flat & 31;
      wT[kk*386 + j] = W[j*256 + k0 + kk];
    }
    __syncthreads();
    #pragma unroll 8
    for(int kk=0;kk<32;kk++){
      float4 s4 = *(const float4*)&sT[kk*36 + rg*4];   // wave-broadcast
      const float* wp = &wT[kk*386 + j0];
      #pragma unroll
      for(int e=0;e<6;e++){
        float wv = wp[e];
        acc[0][e] += s4.x*wv;
        acc[1][e] += s4.y*wv;
        acc[2][e] += s4.z*wv;
        acc[3][e] += s4.w*wv;
      }
    }
  }
  #pragma unroll
  for(int r=0;r<4;r++){
    float s=0.f, ss=0.f;
    #pragma unroll
    for(int e=0;e<6;e++){
      float u = acc[r][e] + bi6[e];
      acc[r][e] = u;
      s += u; ss += u*u;
    }
    #pragma unroll
    for(int msk=32; msk; msk>>=1){ s += __shfl_xor(s,msk); ss += __shfl_xor(ss,msk); }
    float mean = s * (1.f/384.f);
    float var  = fmaxf(ss * (1.f/384.f) - mean*mean, 0.f);
    float rs = rsqrtf(var + 1e-5f);
    int row = row0 + rg*4 + r;
    u32 o01 = (u32)f2bf((acc[r][0]-mean)*rs*g6[0] + b6[0]) | ((u32)f2bf((acc[r][1]-mean)*rs*g6[1] + b6[1]) << 16);
    u32 o23 = (u32)f2bf((acc[r][2]-mean)*rs*g6[2] + b6[2]) | ((u32)f2bf((acc[r][3]-mean)*rs*g6[3] + b6[3]) << 16);
    u32 o45 = (u32)f2bf((acc[r][4]-mean)*rs*g6[4] + b6[4]) | ((u32)f2bf((acc[r][5]-mean)*rs*g6[5] + b6[5]) << 16);
    u32* op = (u32*)(out + row*384 + j0);
    op[0]=o01; op[1]=o23; op[2]=o45;
  }
}

// ---------------- LayerNorm-LSTM scan ----------------
// BL batches per block (one direction per block). Same math as before, but the
// fixed per-step latency (4 barriers + LDS round-trips + dependency stalls,
// ~3500 cyc measured vs ~1300 cyc VALU) is amortized over BL independent
// batch chains sharing the whh registers. Grid: (128/BL, 2).
#define BL 4

__global__ __launch_bounds__(384) void k_lstm(
    const u16* __restrict__ xpf, const u16* __restrict__ xpb,
    const float* __restrict__ fwhh, const float* __restrict__ fbhh, const float* __restrict__ fgh, const float* __restrict__ fbh2,
    const float* __restrict__ fgho, const float* __restrict__ fbho,
    const float* __restrict__ bwhh, const float* __restrict__ bbhh, const float* __restrict__ bgh, const float* __restrict__ bbh2,
    const float* __restrict__ bgho, const float* __restrict__ bbho,
    u16* __restrict__ hcat)
{
  __shared__ __align__(16) float hx[BL][96];      // h state per batch (float4-read)
  __shared__ __align__(16) float gbuf[BL][384];   // post-LN gates per batch
  __shared__ __align__(16) float2 red1[BL][8];    // per-wave (s,ss), 6 used, pad 8
  __shared__ float2 red2[BL][2];                  // cell-LN partials (waves 0,1)
  const int b0  = blockIdx.x * BL;
  const int dir = blockIdx.y;
  const u16* xp;
  const float *whh, *bh, *gh, *bh2, *gho, *bho;
  if(dir == 0){ xp=xpf; whh=fwhh; bh=fbhh; gh=fgh; bh2=fbh2; gho=fgho; bho=fbho; }
  else        { xp=xpb; whh=bwhh; bh=bbhh; gh=bgh; bh2=bbh2; gho=bgho; bho=bbho; }
  const int j = threadIdx.x;
  const int wid = j >> 6;
  float wr[96];                         // whh row j in registers
  {
    const float4* wp4 = (const float4*)(whh + j*96);
    #pragma unroll
    for(int kk=0; kk<24; kk++){
      float4 v = wp4[kk];
      wr[4*kk]=v.x; wr[4*kk+1]=v.y; wr[4*kk+2]=v.z; wr[4*kk+3]=v.w;
    }
  }
  const float bh_j = bh[j], gh_j = gh[j], bh2_j = bh2[j];
  float gho_j = 0.f, bho_j = 0.f;
  if(j < 96){ gho_j = gho[j]; bho_j = bho[j]; }
  float cx[BL];
  #pragma unroll
  for(int bb=0; bb<BL; bb++) cx[bb] = 0.f;
  if(j < 96){
    #pragma unroll
    for(int bb=0; bb<BL; bb++) hx[bb][j] = 0.f;
  }
  __syncthreads();
  for(int t=0; t<512; t++){
    const int ts = dir ? (511 - t) : t;
    float xt[BL];
    #pragma unroll
    for(int bb=0; bb<BL; bb++) xt[bb] = b2f(xp[(ts*128 + b0 + bb)*384 + j]);
    float a[BL][4];
    #pragma unroll
    for(int bb=0; bb<BL; bb++){ a[bb][0]=0.f; a[bb][1]=0.f; a[bb][2]=0.f; a[bb][3]=0.f; }
    #pragma unroll
    for(int kk=0; kk<24; kk++){
      const float wv0 = wr[4*kk], wv1 = wr[4*kk+1], wv2 = wr[4*kk+2], wv3 = wr[4*kk+3];
      #pragma unroll
      for(int bb=0; bb<BL; bb++){
        float4 h4 = ((const float4*)hx[bb])[kk];   // broadcast read
        a[bb][0] += h4.x * wv0;
        a[bb][1] += h4.y * wv1;
        a[bb][2] += h4.z * wv2;
        a[bb][3] += h4.w * wv3;
      }
    }
    float u[BL], s[BL], ss[BL];
    #pragma unroll
    for(int bb=0; bb<BL; bb++){
      u[bb] = (a[bb][0]+a[bb][1]) + (a[bb][2]+a[bb][3]) + bh_j;
      s[bb] = u[bb]; ss[bb] = u[bb]*u[bb];
    }
    #pragma unroll
    for(int msk=32; msk; msk>>=1){
      #pragma unroll
      for(int bb=0; bb<BL; bb++){ s[bb] += __shfl_xor(s[bb],msk); ss[bb] += __shfl_xor(ss[bb],msk); }
    }
    if((j & 63) == 0){
      #pragma unroll
      for(int bb=0; bb<BL; bb++) red1[bb][wid] = make_float2(s[bb], ss[bb]);
    }
    __syncthreads();
    #pragma unroll
    for(int bb=0; bb<BL; bb++){
      const float4* rp = (const float4*)red1[bb];
      float4 r0 = rp[0], r1 = rp[1], r2 = rp[2];
      float S  = (r0.x + r0.z) + (r1.x + r1.z) + (r2.x + r2.z);
      float SS = (r0.y + r0.w) + (r1.y + r1.w) + (r2.y + r2.w);
      const float mean = S*(1.f/384.f);
      const float var  = fmaxf(SS*(1.f/384.f) - mean*mean, 0.f);
      const float rs   = rsqrtf(var + 1e-5f);
      gbuf[bb][j] = xt[bb] + (u[bb] - mean)*rs*gh_j + bh2_j;
    }
    __syncthreads();
    float cy[BL], go_[BL];
    if(j < 128){
      #pragma unroll
      for(int bb=0; bb<BL; bb++){ cy[bb] = 0.f; go_[bb] = 0.f; }
      if(j < 96){
        #pragma unroll
        for(int bb=0; bb<BL; bb++){
          float gi = gbuf[bb][j], gf = gbuf[bb][j+96], gg = gbuf[bb][j+192];
          go_[bb] = gbuf[bb][j+288];
          cy[bb] = sigf(gf)*cx[bb] + sigf(gi)*tanh_(gg);
          cx[bb] = cy[bb];
        }
      }
      float s2[BL], ss2[BL];
      #pragma unroll
      for(int bb=0; bb<BL; bb++){ s2[bb] = cy[bb]; ss2[bb] = cy[bb]*cy[bb]; }
      #pragma unroll
      for(int msk=32; msk; msk>>=1){
        #pragma unroll
        for(int bb=0; bb<BL; bb++){ s2[bb] += __shfl_xor(s2[bb],msk); ss2[bb] += __shfl_xor(ss2[bb],msk); }
      }
      if((j & 63) == 0){
        #pragma unroll
        for(int bb=0; bb<BL; bb++) red2[bb][wid] = make_float2(s2[bb], ss2[bb]);
      }
    }
    __syncthreads();
    if(j < 96){
      #pragma unroll
      for(int bb=0; bb<BL; bb++){
        float2 rA = red2[bb][0], rB = red2[bb][1];
        const float S2 = rA.x + rB.x, SS2 = rA.y + rB.y;
        const float m2  = S2*(1.f/96.f);
        const float v2  = fmaxf(SS2*(1.f/96.f) - m2*m2, 0.f);
        const float rs2 = rsqrtf(v2 + 1e-5f);
        const float lnho = (cy[bb] - m2)*rs2*gho_j + bho_j;
        const float hy = sigf(go_[bb])*tanh_(lnho);
        hx[bb][j] = hy;
        hcat[(ts*128 + b0 + bb)*192 + dir*96 + j] = f2bf(hy);
      }
    }
    __syncthreads();
  }
}

// ---------------- attention + fc1/BN3/ReLU + fc2 (one block per batch) ----------------
__global__ __launch_bounds__(256) void k_head(
    const u16* __restrict__ hcat, const float* __restrict__ aw,
    const float* __restrict__ f1w, const float* __restrict__ f1b,
    const float* __restrict__ g3, const float* __restrict__ b3, const float* __restrict__ m3, const float* __restrict__ v3,
    const float* __restrict__ fc2w, const float* __restrict__ fc2bias,
    float* __restrict__ out)
{
  __shared__ float p[512];
  __shared__ float red[8];
  __shared__ __align__(16) float ctx[192];
  __shared__ float h2[256];
  __shared__ float awl[192];
  const int b = blockIdx.x;
  const int tid = threadIdx.x;
  if(tid < 192) awl[tid] = aw[tid];
  __syncthreads();
  float sc0 = 0.f, sc1 = 0.f;
  #pragma unroll
  for(int i=0;i<2;i++){
    int t = i*256 + tid;
    const uint4* hp = (const uint4*)(hcat + (t*128 + b)*192);
    float acc = 0.f;
    #pragma unroll 6
    for(int qq=0;qq<24;qq++){
      uint4 pv = hp[qq];
      acc += b2f((u16)(pv.x&0xffffu))*awl[qq*8+0] + b2f((u16)(pv.x>>16))*awl[qq*8+1]
           + b2f((u16)(pv.y&0xffffu))*awl[qq*8+2] + b2f((u16)(pv.y>>16))*awl[qq*8+3]
           + b2f((u16)(pv.z&0xffffu))*awl[qq*8+4] + b2f((u16)(pv.z>>16))*awl[qq*8+5]
           + b2f((u16)(pv.w&0xffffu))*awl[qq*8+6] + b2f((u16)(pv.w>>16))*awl[qq*8+7];
    }
    if(i==0) sc0 = acc; else sc1 = acc;
  }
  float mx = fmaxf(sc0, sc1);
  for(int msk=32; msk; msk>>=1) mx = fmaxf(mx, __shfl_xor(mx,msk));
  if((tid&63)==0) red[tid>>6] = mx;
  __syncthreads();
  mx = fmaxf(fmaxf(red[0],red[1]), fmaxf(red[2],red[3]));
  float e0 = __expf(sc0-mx), e1 = __expf(sc1-mx);
  float sm = e0 + e1;
  for(int msk=32; msk; msk>>=1) sm += __shfl_xor(sm,msk);
  if((tid&63)==0) red[4 + (tid>>6)] = sm;
  __syncthreads();
  const float inv = 1.f/(red[4]+red[5]+red[6]+red[7]);
  p[tid] = e0*inv; p[tid+256] = e1*inv;
  __syncthreads();
  if(tid < 192){
    float acc = 0.f;
    for(int t=0;t<512;t++){
      acc += p[t] * b2f(hcat[(t*128 + b)*192 + tid]);
    }
    ctx[tid] = acc;
  }
  __syncthreads();
  {
    const float4* cv = (const float4*)ctx;
    const float4* wp = (const float4*)(f1w + tid*192);
    float acc = 0.f;
    #pragma unroll 8
    for(int qq=0;qq<48;qq++){
      acc += dot4(wp[qq], cv[qq]);
    }
    acc += f1b[tid];
    float a = g3[tid] * rsqrtf(v3[tid] + 1e-5f);
    float y = (acc - m3[tid])*a + b3[tid];
    h2[tid] = fmaxf(y, 0.f);
  }
  __syncthreads();
  if(tid < 6){
    float acc = fc2bias[tid];
    for(int k=0;k<256;k++) acc += h2[k]*fc2w[tid*256 + k];
    out[b*6 + tid] = acc;
  }
}

extern "C" void kernel_launch(void* const* d_in, const int* in_sizes, int n_in,
                              void* d_out, int out_size, void* d_ws, size_t ws_size,
                              hipStream_t stream)
{
  (void)in_sizes; (void)n_in; (void)out_size; (void)ws_size;
  const float* X      = (const float*)d_in[0];
  const float* c1w    = (const float*)d_in[1];
  const float* c1b    = (const float*)d_in[2];
  const float* bn1g   = (const float*)d_in[3];
  const float* bn1b   = (const float*)d_in[4];
  const float* bn1m   = (const float*)d_in[5];
  const float* bn1v   = (const float*)d_in[6];
  const float* c2w    = (const float*)d_in[7];
  const float* c2b    = (const float*)d_in[8];
  const float* bn2g   = (const float*)d_in[9];
  const float* bn2b   = (const float*)d_in[10];
  const float* bn2m   = (const float*)d_in[11];
  const float* bn2v   = (const float*)d_in[12];
  const float* fwih   = (const float*)d_in[13];
  const float* fbih   = (const float*)d_in[14];
  const float* fwhh   = (const float*)d_in[15];
  const float* fbhh   = (const float*)d_in[16];
  const float* flnihg = (const float*)d_in[17];
  const float* flnihb = (const float*)d_in[18];
  const float* flnhhg = (const float*)d_in[19];
  const float* flnhhb = (const float*)d_in[20];
  const float* flnhog = (const float*)d_in[21];
  const float* flnhob = (const float*)d_in[22];
  const float* bwih   = (const float*)d_in[23];
  const float* bbih   = (const float*)d_in[24];
  const float* bwhh   = (const float*)d_in[25];
  const float* bbhh   = (const float*)d_in[26];
  const float* blnihg = (const float*)d_in[27];
  const float* blnihb = (const float*)d_in[28];
  const float* blnhhg = (const float*)d_in[29];
  const float* blnhhb = (const float*)d_in[30];
  const float* blnhog = (const float*)d_in[31];
  const float* blnhob = (const float*)d_in[32];
  const float* attnw  = (const float*)d_in[33];
  const float* fc1w   = (const float*)d_in[34];
  const float* fc1b   = (const float*)d_in[35];
  const float* bn3g   = (const float*)d_in[36];
  const float* bn3b   = (const float*)d_in[37];
  const float* bn3m   = (const float*)d_in[38];
  const float* bn3v   = (const float*)d_in[39];
  const float* fc2w   = (const float*)d_in[40];
  const float* fc2b_  = (const float*)d_in[41];

  // Workspace layout (peak 128 MiB), liveness-based overlays:
  //   seq  @   0 .. 32M   (conv2 out; dead after k_xp)
  //   xpf  @  32M .. 80M
  //   xpb  @  80M ..128M
  //   c1o  @  96M ..128M  (conv1 out; dead after conv2)   [xpb written after c1o is dead]
  //   hcat @   0 .. 24M   (lstm out; overlays dead seq)
  char* ws = (char*)d_ws;
  const size_t MB = 1048576;
  u16* seq  = (u16*)(ws);
  u16* xpf  = (u16*)(ws + 32*MB);
  u16* xpb  = (u16*)(ws + 80*MB);
  u16* c1o  = (u16*)(ws + 96*MB);
  u16* hcat = (u16*)(ws);

  k_conv1<<<dim3(8,128),  256, 0, stream>>>(X,   c1w, c1b, bn1g, bn1b, bn1m, bn1v, c1o);
  k_conv2<<<dim3(8,4,128),256, 0, stream>>>(c1o, c2w, c2b, bn2g, bn2b, bn2m, bn2v, seq);
  k_xp  <<<dim3(2048,2),  512, 0, stream>>>(seq, fwih, fbih, flnihg, flnihb,
                                                 bwih, bbih, blnihg, blnihb, xpf, xpb);
  k_lstm<<<dim3(128/BL,2),384, 0, stream>>>(xpf, xpb,
      fwhh, fbhh, flnhhg, flnhhb, flnhog, flnhob,
      bwhh, bbhh, blnhhg, blnhhb, blnhog, blnhob, hcat);
  k_head<<<dim3(128),     256, 0, stream>>>(hcat, attnw, fc1w, fc1b,
      bn3g, bn3b, bn3m, bn3v, fc2w, fc2b_, (float*)d_out);
}

// Round 2
// 2332.784 us; speedup vs baseline: 1.8428x; 1.8428x over previous
//
#include <hip/hip_runtime.h>

typedef unsigned short u16;
typedef unsigned int   u32;

#define DI __device__ __forceinline__

DI float b2f(u16 u){ union{u32 i; float f;} x; x.i = ((u32)u)<<16; return x.f; }
DI u16 f2bf(float f){ union{float f; u32 i;} x; x.f=f; u32 r = x.i + 0x7FFFu + ((x.i>>16)&1u); return (u16)(r>>16); }
DI float sigf(float x){ return 1.0f/(1.0f + __expf(-x)); }
DI float tanh_(float x){ return 1.0f - 2.0f/(__expf(2.0f*x)+1.0f); }
DI float dot4(float4 a, float4 b){ return a.x*b.x + a.y*b.y + a.z*b.z + a.w*b.w; }

// ---------------- conv1 (k=7,pad3) + BN1 + ReLU + maxpool2 ----------------
// x: [128][2048][8] f32  -> out: [128][128][1024] bf16  (layout [b][co][t'])
__global__ __launch_bounds__(256) void k_conv1(
    const float* __restrict__ x, const float* __restrict__ w,
    const float* __restrict__ cb, const float* __restrict__ bg, const float* __restrict__ bb,
    const float* __restrict__ bm, const float* __restrict__ bv, u16* __restrict__ out)
{
  __shared__ __align__(16) float xs[262*8];
  __shared__ __align__(16) float wl[128*7*8];   // [co][k][ci]
  __shared__ float As[128], Ss[128];
  const int tid = threadIdx.x;
  const int tc  = blockIdx.x;       // 8 chunks of 128 pooled positions
  const int b   = blockIdx.y;
  const int tau0 = tc*256;
  for(int f = tid; f < 262*8; f += 256){
    int tt = f >> 3;
    int ci = f & 7;
    int xg = tau0 - 3 + tt;
    float val = 0.f;
    if(xg >= 0 && xg < 2048) val = x[(b*2048 + xg)*8 + ci];
    xs[f] = val;
  }
  for(int d = tid; d < 128*7*8; d += 256){
    int co = d / 56; int r = d - co*56; int k = r >> 3; int ci = r & 7;
    wl[d] = w[(co*8 + ci)*7 + k];
  }
  if(tid < 128){
    float a = bg[tid] * rsqrtf(bv[tid] + 1e-5f);
    As[tid] = a;
    Ss[tid] = (cb[tid] - bm[tid])*a + bb[tid];
  }
  __syncthreads();
  const float4* xs4 = (const float4*)xs;
  const float4* wl4 = (const float4*)wl;
  for(int i = 0; i < 64; i++){
    int idx = i*256 + tid;
    int co = idx >> 7, p = idx & 127;
    float4 xa[8], xb[8];
    #pragma unroll
    for(int d=0; d<8; d++){ xa[d] = xs4[(2*p + d)*2]; xb[d] = xs4[(2*p + d)*2 + 1]; }
    float a0 = 0.f, a1 = 0.f;
    #pragma unroll
    for(int k=0;k<7;k++){
      float4 wa = wl4[(co*7+k)*2], wb = wl4[(co*7+k)*2+1];
      a0 += dot4(xa[k],   wa) + dot4(xb[k],   wb);
      a1 += dot4(xa[k+1], wa) + dot4(xb[k+1], wb);
    }
    float Ac = As[co], Sc = Ss[co];
    float y = fmaxf(fmaxf(a0*Ac+Sc, a1*Ac+Sc), 0.f);
    out[((b*128 + co)<<10) + tc*128 + p] = f2bf(y);
  }
}

// ---------------- conv2 (k=5,pad2) + BN2 + ReLU + maxpool2 ----------------
// in: [128][128][1024] bf16 -> seq: [512][128][256] bf16 (layout [t'][b][co])
__global__ __launch_bounds__(256) void k_conv2(
    const u16* __restrict__ cin, const float* __restrict__ w,
    const float* __restrict__ cb, const float* __restrict__ bg, const float* __restrict__ bb,
    const float* __restrict__ bm, const float* __restrict__ bv, u16* __restrict__ seq)
{
  __shared__ __align__(16) float xs[16*132];
  __shared__ __align__(16) float wl[64*16*8];   // [c][ci][k(pad8)]
  __shared__ float As[64], Ss[64];
  const int tid = threadIdx.x;
  const int tc  = blockIdx.x;    // 0..7  (64 pooled t' per chunk)
  const int cog = blockIdx.y;    // 0..3  (64 co per group)
  const int b   = blockIdx.z;
  const int co0 = cog*64;
  const int tau0 = tc*128;
  if(tid < 64){
    int co = co0 + tid;
    float a = bg[co] * rsqrtf(bv[co] + 1e-5f);
    As[tid] = a; Ss[tid] = (cb[co] - bm[co])*a + bb[co];
  }
  const int q  = tid & 15;       // t' group of 4
  const int cg = tid >> 4;       // co group of 4
  float acc[4][4][2];
  #pragma unroll
  for(int c=0;c<4;c++)
    #pragma unroll
    for(int tl=0;tl<4;tl++){ acc[c][tl][0]=0.f; acc[c][tl][1]=0.f; }
  for(int ci0 = 0; ci0 < 128; ci0 += 16){
    __syncthreads();
    for(int f = tid; f < 16*132; f += 256){
      int ci = f / 132, tt = f - ci*132;
      int tg = tau0 + tt - 2;
      float val = 0.f;
      if(tg >= 0 && tg < 1024) val = b2f(cin[((b*128 + ci0+ci)<<10) + tg]);
      xs[f] = val;
    }
    for(int f = tid; f < 64*16*5; f += 256){
      int c = f / 80; int r = f - c*80; int ci = r/5; int k = r - ci*5;
      wl[(c*16+ci)*8 + k] = w[((co0+c)*128 + ci0+ci)*5 + k];
    }
    __syncthreads();
    #pragma unroll 4
    for(int ci = 0; ci < 16; ci++){
      const float4* xr = (const float4*)&xs[ci*132 + 8*q];
      float4 x0 = xr[0], x1 = xr[1], x2 = xr[2];
      float xv[12];
      xv[0]=x0.x; xv[1]=x0.y; xv[2]=x0.z; xv[3]=x0.w;
      xv[4]=x1.x; xv[5]=x1.y; xv[6]=x1.z; xv[7]=x1.w;
      xv[8]=x2.x; xv[9]=x2.y; xv[10]=x2.z; xv[11]=x2.w;
      #pragma unroll
      for(int c=0;c<4;c++){
        const float* wp = &wl[((cg*4+c)*16 + ci)*8];
        float w0=wp[0], w1=wp[1], w2=wp[2], w3=wp[3], w4=wp[4];
        #pragma unroll
        for(int tl=0; tl<4; tl++){
          acc[c][tl][0] += xv[2*tl+0]*w0 + xv[2*tl+1]*w1 + xv[2*tl+2]*w2 + xv[2*tl+3]*w3 + xv[2*tl+4]*w4;
          acc[c][tl][1] += xv[2*tl+1]*w0 + xv[2*tl+2]*w1 + xv[2*tl+3]*w2 + xv[2*tl+4]*w3 + xv[2*tl+5]*w4;
        }
      }
    }
  }
  #pragma unroll
  for(int c=0;c<4;c++){
    float Ac = As[cg*4+c], Sc = Ss[cg*4+c];
    #pragma unroll
    for(int tl=0;tl<4;tl++){
      float y0 = acc[c][tl][0]*Ac + Sc;
      float y1 = acc[c][tl][1]*Ac + Sc;
      float y  = fmaxf(fmaxf(y0, y1), 0.f);
      int tp = tc*64 + q*4 + tl;
      seq[(tp*128 + b)*256 + co0 + cg*4 + c] = f2bf(y);
    }
  }
}

// ---------------- xp = LN(seq @ wih.T + bih)  (per direction) ----------------
// seq: [65536 rows][256] bf16 ; wih: [384][256] f32 ; out xp: [rows][384] bf16
__global__ __launch_bounds__(512) void k_xp(
    const u16* __restrict__ seq,
    const float* __restrict__ fw, const float* __restrict__ fbi, const float* __restrict__ fg, const float* __restrict__ fb,
    const float* __restrict__ bw, const float* __restrict__ bbi, const float* __restrict__ bg_, const float* __restrict__ bb_,
    u16* __restrict__ xpf, u16* __restrict__ xpb)
{
  __shared__ __align__(16) float sT[32*36];     // [k][r] pitch 36
  __shared__ __align__(16) float wT[32*386];    // [k][j] pitch 386
  const float *W, *BI, *LG, *LB; u16* out;
  if(blockIdx.y == 0){ W=fw; BI=fbi; LG=fg;  LB=fb;  out=xpf; }
  else               { W=bw; BI=bbi; LG=bg_; LB=bb_; out=xpb; }
  const int tid = threadIdx.x;
  const int row0 = blockIdx.x * 32;
  const int jg = tid & 63, rg = tid >> 6;       // wave rg owns rows rg*4..+3
  const int j0 = jg*6;
  float bi6[6], g6[6], b6[6];
  #pragma unroll
  for(int e=0;e<6;e++){ bi6[e]=BI[j0+e]; g6[e]=LG[j0+e]; b6[e]=LB[j0+e]; }
  float acc[4][6];
  #pragma unroll
  for(int r=0;r<4;r++)
    #pragma unroll
    for(int e=0;e<6;e++) acc[r][e]=0.f;
  for(int k0=0;k0<256;k0+=32){
    __syncthreads();
    {
      int r = tid >> 4; int kk = (tid & 15)*2;
      u32 pv = *(const u32*)&seq[(row0 + r)*256 + k0 + kk];
      sT[kk*36 + r]     = b2f((u16)(pv & 0xffffu));
      sT[(kk+1)*36 + r] = b2f((u16)(pv >> 16));
    }
    #pragma unroll
    for(int rep=0; rep<24; rep++){
      int flat = rep*512 + tid;                 // 0..12287 = 384*32
      int j = flat >> 5; int kk = flat & 31;
      wT[kk*386 + j] = W[j*256 + k0 + kk];
    }
    __syncthreads();
    #pragma unroll 8
    for(int kk=0;kk<32;kk++){
      float4 s4 = *(const float4*)&sT[kk*36 + rg*4];   // wave-broadcast
      const float* wp = &wT[kk*386 + j0];
      #pragma unroll
      for(int e=0;e<6;e++){
        float wv = wp[e];
        acc[0][e] += s4.x*wv;
        acc[1][e] += s4.y*wv;
        acc[2][e] += s4.z*wv;
        acc[3][e] += s4.w*wv;
      }
    }
  }
  #pragma unroll
  for(int r=0;r<4;r++){
    float s=0.f, ss=0.f;
    #pragma unroll
    for(int e=0;e<6;e++){
      float u = acc[r][e] + bi6[e];
      acc[r][e] = u;
      s += u; ss += u*u;
    }
    #pragma unroll
    for(int msk=32; msk; msk>>=1){ s += __shfl_xor(s,msk); ss += __shfl_xor(ss,msk); }
    float mean = s * (1.f/384.f);
    float var  = fmaxf(ss * (1.f/384.f) - mean*mean, 0.f);
    float rs = rsqrtf(var + 1e-5f);
    int row = row0 + rg*4 + r;
    u32 o01 = (u32)f2bf((acc[r][0]-mean)*rs*g6[0] + b6[0]) | ((u32)f2bf((acc[r][1]-mean)*rs*g6[1] + b6[1]) << 16);
    u32 o23 = (u32)f2bf((acc[r][2]-mean)*rs*g6[2] + b6[2]) | ((u32)f2bf((acc[r][3]-mean)*rs*g6[3] + b6[3]) << 16);
    u32 o45 = (u32)f2bf((acc[r][4]-mean)*rs*g6[4] + b6[4]) | ((u32)f2bf((acc[r][5]-mean)*rs*g6[5] + b6[5]) << 16);
    u32* op = (u32*)(out + row*384 + j0);
    op[0]=o01; op[1]=o23; op[2]=o45;
  }
}

// ---------------- LayerNorm-LSTM scan (one block per (batch,dir)) ----------------
// Quad-permuted row assignment: thread j computes gate row r=(j&3)*96+(j>>2),
// so all 4 gates of hidden m=j>>2 live on one lane-quad -> the gate exchange is
// 3 shfl_xor + cndmasks (no gbuf LDS round-trip, no extra barrier).
// 3 barriers/step; hx preloaded into registers in one burst; xt register
// double-buffered; hcat staged in LDS, flushed every 16 steps (store-ack
// vmcnt drain 32x/kernel instead of 512x).
__global__ __launch_bounds__(384, 1) void k_lstm(
    const u16* __restrict__ xpf, const u16* __restrict__ xpb,
    const float* __restrict__ fwhh, const float* __restrict__ fbhh, const float* __restrict__ fgh, const float* __restrict__ fbh2,
    const float* __restrict__ fgho, const float* __restrict__ fbho,
    const float* __restrict__ bwhh, const float* __restrict__ bbhh, const float* __restrict__ bgh, const float* __restrict__ bbh2,
    const float* __restrict__ bgho, const float* __restrict__ bbho,
    u16* __restrict__ hcat)
{
  __shared__ __align__(16) float hx[96];       // h state, f32
  __shared__ __align__(16) float2 red1[8];     // LN1 wave partials (6 used)
  __shared__ __align__(16) float2 red2[8];     // LN2 wave partials (6 used)
  __shared__ __align__(16) u16 hstage[16][96]; // hcat staging (16 steps)
  const int b   = blockIdx.x;
  const int dir = blockIdx.y;
  const u16* xp;
  const float *whh, *bh, *gh, *bh2, *gho, *bho;
  if(dir == 0){ xp=xpf; whh=fwhh; bh=fbhh; gh=fgh; bh2=fbh2; gho=fgho; bho=fbho; }
  else        { xp=xpb; whh=bwhh; bh=bbhh; gh=bgh; bh2=bbh2; gho=bgho; bho=bbho; }
  const int j    = threadIdx.x;
  const int wid  = j >> 6;
  const int lane = j & 63;
  const int q    = j & 3;        // gate index (0=i,1=f,2=g,3=o)
  const int m    = j >> 2;       // hidden index 0..95
  const int r    = q*96 + m;     // gate row this thread computes
  float wr[96];                  // whh row r in registers
  {
    const float4* wp4 = (const float4*)(whh + r*96);
    #pragma unroll
    for(int kk=0; kk<24; kk++){
      float4 v = wp4[kk];
      wr[4*kk]=v.x; wr[4*kk+1]=v.y; wr[4*kk+2]=v.z; wr[4*kk+3]=v.w;
    }
  }
  const float bh_r = bh[r], gh_r = gh[r], bh2_r = bh2[r];
  const float gho_m = gho[m], bho_m = bho[m];
  float cx = 0.f;
  if(j < 96) hx[j] = 0.f;
  if(j < 2){ red1[6+j] = make_float2(0.f,0.f); red2[6+j] = make_float2(0.f,0.f); }
  const u16* xrow = xp + b*384 + r;              // + ts*49152 per step
  float xt_cur = b2f(xrow[(dir ? 511 : 0)*49152]);
  __syncthreads();
  for(int t=0; t<512; t++){
    const int ts = dir ? (511 - t) : t;
    // prefetch next timestep's xt (drained at B1, ~1000cyc after issue)
    float xt_next = 0.f;
    if(t < 511){
      const int ts2 = dir ? (510 - t) : (t + 1);
      xt_next = b2f(xrow[ts2*49152]);
    }
    // ---- phase A: burst-load hx, matvec u_r = whh[r,:] . hx ----
    float4 h4[24];
    {
      const float4* hp = (const float4*)hx;
      #pragma unroll
      for(int kk=0; kk<24; kk++) h4[kk] = hp[kk];
    }
    float a0=0.f, a1=0.f, a2=0.f, a3=0.f;
    #pragma unroll
    for(int kk=0; kk<24; kk++){
      a0 += h4[kk].x * wr[4*kk];
      a1 += h4[kk].y * wr[4*kk+1];
      a2 += h4[kk].z * wr[4*kk+2];
      a3 += h4[kk].w * wr[4*kk+3];
    }
    const float u = (a0+a1)+(a2+a3) + bh_r;
    // ---- LN1 over all 384 rows ----
    float s = u, ss = u*u;
    #pragma unroll
    for(int msk=32; msk; msk>>=1){ s += __shfl_xor(s,msk); ss += __shfl_xor(ss,msk); }
    if(lane == 0) red1[wid] = make_float2(s, ss);
    __syncthreads();                             // B1
    float gate;
    {
      const float4* rp = (const float4*)red1;
      float4 p0 = rp[0], p1 = rp[1], p2 = rp[2];
      float S  = (p0.x + p0.z) + (p1.x + p1.z) + (p2.x + p2.z);
      float SS = (p0.y + p0.w) + (p1.y + p1.w) + (p2.y + p2.w);
      const float mean = S*(1.f/384.f);
      const float var  = fmaxf(SS*(1.f/384.f) - mean*mean, 0.f);
      const float rs   = rsqrtf(var + 1e-5f);
      gate = xt_cur + (u - mean)*rs*gh_r + bh2_r;
    }
    // ---- quad exchange: collect i,f,g,o of hidden m onto every lane of quad ----
    const float x1 = __shfl_xor(gate, 1);        // gate index q^1
    const float x2 = __shfl_xor(gate, 2);        // q^2
    const float x3 = __shfl_xor(x1,   2);        // q^3
    const bool qb0 = (q & 1), qb1 = (q & 2);
    const float lo0 = qb0 ? x1 : gate;           // gate with bit0=0 among {q,q^1}
    const float lo1 = qb0 ? gate : x1;
    const float hi0 = qb0 ? x3 : x2;
    const float hi1 = qb0 ? x2 : x3;
    const float gi = qb1 ? hi0 : lo0;            // gate 0 (input)
    const float gf = qb1 ? hi1 : lo1;            // gate 1 (forget)
    const float gg = qb1 ? lo0 : hi0;            // gate 2 (cell)
    const float go = qb1 ? lo1 : hi1;            // gate 3 (out)
    // ---- cell update (redundant across the 4 lanes of the quad) ----
    const float cy = sigf(gf)*cx + sigf(gi)*tanh_(gg);
    cx = cy;
    // ---- LN2 over 96 cy: masks >=4 sum the 16 distinct per wave ----
    float s2 = cy, ss2 = cy*cy;
    #pragma unroll
    for(int msk=4; msk<64; msk<<=1){ s2 += __shfl_xor(s2,msk); ss2 += __shfl_xor(ss2,msk); }
    if(lane == 0) red2[wid] = make_float2(s2, ss2);
    __syncthreads();                             // B2
    {
      const float4* rp = (const float4*)red2;
      float4 p0 = rp[0], p1 = rp[1], p2 = rp[2];
      float S2  = (p0.x + p0.z) + (p1.x + p1.z) + (p2.x + p2.z);
      float SS2 = (p0.y + p0.w) + (p1.y + p1.w) + (p2.y + p2.w);
      const float m2  = S2*(1.f/96.f);
      const float v2  = fmaxf(SS2*(1.f/96.f) - m2*m2, 0.f);
      const float rs2 = rsqrtf(v2 + 1e-5f);
      const float lnho = (cy - m2)*rs2*gho_m + bho_m;
      const float hy = sigf(go)*tanh_(lnho);
      if(q == 0){
        hx[m] = hy;
        hstage[t & 15][m] = f2bf(hy);
      }
    }
    xt_cur = xt_next;
    __syncthreads();                             // B3 (hx/hstage ready)
    if((t & 15) == 15){
      // flush 16 staged steps: 16 rows x 12 uint4 chunks = 192 workers
      if(j < 192){
        const int row = j / 12, ch = j - row*12;
        const int tbase = t - 15;
        const int tsr = dir ? (511 - (tbase + row)) : (tbase + row);
        uint4 v = *(const uint4*)&hstage[row][ch*8];
        *(uint4*)&hcat[(tsr*128 + b)*192 + dir*96 + ch*8] = v;
      }
    }
  }
}

// ---------------- attention + fc1/BN3/ReLU + fc2 (one block per batch) ----------------
__global__ __launch_bounds__(256) void k_head(
    const u16* __restrict__ hcat, const float* __restrict__ aw,
    const float* __restrict__ f1w, const float* __restrict__ f1b,
    const float* __restrict__ g3, const float* __restrict__ b3, const float* __restrict__ m3, const float* __restrict__ v3,
    const float* __restrict__ fc2w, const float* __restrict__ fc2bias,
    float* __restrict__ out)
{
  __shared__ float p[512];
  __shared__ float red[8];
  __shared__ __align__(16) float ctx[192];
  __shared__ float h2[256];
  __shared__ float awl[192];
  const int b = blockIdx.x;
  const int tid = threadIdx.x;
  if(tid < 192) awl[tid] = aw[tid];
  __syncthreads();
  float sc0 = 0.f, sc1 = 0.f;
  #pragma unroll
  for(int i=0;i<2;i++){
    int t = i*256 + tid;
    const uint4* hp = (const uint4*)(hcat + (t*128 + b)*192);
    float acc = 0.f;
    #pragma unroll 6
    for(int qq=0;qq<24;qq++){
      uint4 pv = hp[qq];
      acc += b2f((u16)(pv.x&0xffffu))*awl[qq*8+0] + b2f((u16)(pv.x>>16))*awl[qq*8+1]
           + b2f((u16)(pv.y&0xffffu))*awl[qq*8+2] + b2f((u16)(pv.y>>16))*awl[qq*8+3]
           + b2f((u16)(pv.z&0xffffu))*awl[qq*8+4] + b2f((u16)(pv.z>>16))*awl[qq*8+5]
           + b2f((u16)(pv.w&0xffffu))*awl[qq*8+6] + b2f((u16)(pv.w>>16))*awl[qq*8+7];
    }
    if(i==0) sc0 = acc; else sc1 = acc;
  }
  float mx = fmaxf(sc0, sc1);
  for(int msk=32; msk; msk>>=1) mx = fmaxf(mx, __shfl_xor(mx,msk));
  if((tid&63)==0) red[tid>>6] = mx;
  __syncthreads();
  mx = fmaxf(fmaxf(red[0],red[1]), fmaxf(red[2],red[3]));
  float e0 = __expf(sc0-mx), e1 = __expf(sc1-mx);
  float sm = e0 + e1;
  for(int msk=32; msk; msk>>=1) sm += __shfl_xor(sm,msk);
  if((tid&63)==0) red[4 + (tid>>6)] = sm;
  __syncthreads();
  const float inv = 1.f/(red[4]+red[5]+red[6]+red[7]);
  p[tid] = e0*inv; p[tid+256] = e1*inv;
  __syncthreads();
  if(tid < 192){
    float acc = 0.f;
    for(int t=0;t<512;t++){
      acc += p[t] * b2f(hcat[(t*128 + b)*192 + tid]);
    }
    ctx[tid] = acc;
  }
  __syncthreads();
  {
    const float4* cv = (const float4*)ctx;
    const float4* wp = (const float4*)(f1w + tid*192);
    float acc = 0.f;
    #pragma unroll 8
    for(int qq=0;qq<48;qq++){
      acc += dot4(wp[qq], cv[qq]);
    }
    acc += f1b[tid];
    float a = g3[tid] * rsqrtf(v3[tid] + 1e-5f);
    float y = (acc - m3[tid])*a + b3[tid];
    h2[tid] = fmaxf(y, 0.f);
  }
  __syncthreads();
  if(tid < 6){
    float acc = fc2bias[tid];
    for(int k=0;k<256;k++) acc += h2[k]*fc2w[tid*256 + k];
    out[b*6 + tid] = acc;
  }
}

extern "C" void kernel_launch(void* const* d_in, const int* in_sizes, int n_in,
                              void* d_out, int out_size, void* d_ws, size_t ws_size,
                              hipStream_t stream)
{
  (void)in_sizes; (void)n_in; (void)out_size; (void)ws_size;
  const float* X      = (const float*)d_in[0];
  const float* c1w    = (const float*)d_in[1];
  const float* c1b    = (const float*)d_in[2];
  const float* bn1g   = (const float*)d_in[3];
  const float* bn1b   = (const float*)d_in[4];
  const float* bn1m   = (const float*)d_in[5];
  const float* bn1v   = (const float*)d_in[6];
  const float* c2w    = (const float*)d_in[7];
  const float* c2b    = (const float*)d_in[8];
  const float* bn2g   = (const float*)d_in[9];
  const float* bn2b   = (const float*)d_in[10];
  const float* bn2m   = (const float*)d_in[11];
  const float* bn2v   = (const float*)d_in[12];
  const float* fwih   = (const float*)d_in[13];
  const float* fbih   = (const float*)d_in[14];
  const float* fwhh   = (const float*)d_in[15];
  const float* fbhh   = (const float*)d_in[16];
  const float* flnihg = (const float*)d_in[17];
  const float* flnihb = (const float*)d_in[18];
  const float* flnhhg = (const float*)d_in[19];
  const float* flnhhb = (const float*)d_in[20];
  const float* flnhog = (const float*)d_in[21];
  const float* flnhob = (const float*)d_in[22];
  const float* bwih   = (const float*)d_in[23];
  const float* bbih   = (const float*)d_in[24];
  const float* bwhh   = (const float*)d_in[25];
  const float* bbhh   = (const float*)d_in[26];
  const float* blnihg = (const float*)d_in[27];
  const float* blnihb = (const float*)d_in[28];
  const float* blnhhg = (const float*)d_in[29];
  const float* blnhhb = (const float*)d_in[30];
  const float* blnhog = (const float*)d_in[31];
  const float* blnhob = (const float*)d_in[32];
  const float* attnw  = (const float*)d_in[33];
  const float* fc1w   = (const float*)d_in[34];
  const float* fc1b   = (const float*)d_in[35];
  const float* bn3g   = (const float*)d_in[36];
  const float* bn3b   = (const float*)d_in[37];
  const float* bn3m   = (const float*)d_in[38];
  const float* bn3v   = (const float*)d_in[39];
  const float* fc2w   = (const float*)d_in[40];
  const float* fc2b_  = (const float*)d_in[41];

  // Workspace layout (peak 128 MiB), liveness-based overlays:
  //   seq  @   0 .. 32M   (conv2 out; dead after k_xp)
  //   xpf  @  32M .. 80M
  //   xpb  @  80M ..128M
  //   c1o  @  96M ..128M  (conv1 out; dead after conv2)   [xpb written after c1o is dead]
  //   hcat @   0 .. 24M   (lstm out; overlays dead seq)
  char* ws = (char*)d_ws;
  const size_t MB = 1048576;
  u16* seq  = (u16*)(ws);
  u16* xpf  = (u16*)(ws + 32*MB);
  u16* xpb  = (u16*)(ws + 80*MB);
  u16* c1o  = (u16*)(ws + 96*MB);
  u16* hcat = (u16*)(ws);

  k_conv1<<<dim3(8,128),  256, 0, stream>>>(X,   c1w, c1b, bn1g, bn1b, bn1m, bn1v, c1o);
  k_conv2<<<dim3(8,4,128),256, 0, stream>>>(c1o, c2w, c2b, bn2g, bn2b, bn2m, bn2v, seq);
  k_xp  <<<dim3(2048,2),  512, 0, stream>>>(seq, fwih, fbih, flnihg, flnihb,
                                                 bwih, bbih, blnihg, blnihb, xpf, xpb);
  k_lstm<<<dim3(128,2),   384, 0, stream>>>(xpf, xpb,
      fwhh, fbhh, flnhhg, flnhhb, flnhog, flnhob,
      bwhh, bbhh, blnhhg, blnhhb, blnhog, blnhob, hcat);
  k_head<<<dim3(128),     256, 0, stream>>>(hcat, attnw, fc1w, fc1b,
      bn3g, bn3b, bn3m, bn3v, fc2w, fc2b_, (float*)d_out);
}

// Round 4
// 2154.172 us; speedup vs baseline: 1.9956x; 1.0829x over previous
//
#include <hip/hip_runtime.h>

typedef unsigned short u16;
typedef unsigned int   u32;
typedef __attribute__((ext_vector_type(8))) short bf16x8;
typedef __attribute__((ext_vector_type(4))) float f32x4;

#define DI __device__ __forceinline__

DI float b2f(u16 u){ union{u32 i; float f;} x; x.i = ((u32)u)<<16; return x.f; }
DI u16 f2bf(float f){ union{float f; u32 i;} x; x.f=f; u32 r = x.i + 0x7FFFu + ((x.i>>16)&1u); return (u16)(r>>16); }
DI float sigf(float x){ return 1.0f/(1.0f + __expf(-x)); }
DI float tanh_(float x){ return 1.0f - 2.0f/(__expf(2.0f*x)+1.0f); }
DI float dot4(float4 a, float4 b){ return a.x*b.x + a.y*b.y + a.z*b.z + a.w*b.w; }

// ---------------- conv1 (k=7,pad3) + BN1 + ReLU + maxpool2 ----------------
// x: [128][2048][8] f32  -> out: [128][128][1024] bf16  (layout [b][co][t'])
__global__ __launch_bounds__(256) void k_conv1(
    const float* __restrict__ x, const float* __restrict__ w,
    const float* __restrict__ cb, const float* __restrict__ bg, const float* __restrict__ bb,
    const float* __restrict__ bm, const float* __restrict__ bv, u16* __restrict__ out)
{
  __shared__ __align__(16) float xs[262*8];
  __shared__ __align__(16) float wl[128*7*8];   // [co][k][ci]
  __shared__ float As[128], Ss[128];
  const int tid = threadIdx.x;
  const int tc  = blockIdx.x;       // 8 chunks of 128 pooled positions
  const int b   = blockIdx.y;
  const int tau0 = tc*256;
  for(int f = tid; f < 262*8; f += 256){
    int tt = f >> 3;
    int ci = f & 7;
    int xg = tau0 - 3 + tt;
    float val = 0.f;
    if(xg >= 0 && xg < 2048) val = x[(b*2048 + xg)*8 + ci];
    xs[f] = val;
  }
  for(int d = tid; d < 128*7*8; d += 256){
    int co = d / 56; int r = d - co*56; int k = r >> 3; int ci = r & 7;
    wl[d] = w[(co*8 + ci)*7 + k];
  }
  if(tid < 128){
    float a = bg[tid] * rsqrtf(bv[tid] + 1e-5f);
    As[tid] = a;
    Ss[tid] = (cb[tid] - bm[tid])*a + bb[tid];
  }
  __syncthreads();
  const float4* xs4 = (const float4*)xs;
  const float4* wl4 = (const float4*)wl;
  for(int i = 0; i < 64; i++){
    int idx = i*256 + tid;
    int co = idx >> 7, p = idx & 127;
    float4 xa[8], xb[8];
    #pragma unroll
    for(int d=0; d<8; d++){ xa[d] = xs4[(2*p + d)*2]; xb[d] = xs4[(2*p + d)*2 + 1]; }
    float a0 = 0.f, a1 = 0.f;
    #pragma unroll
    for(int k=0;k<7;k++){
      float4 wa = wl4[(co*7+k)*2], wb = wl4[(co*7+k)*2+1];
      a0 += dot4(xa[k],   wa) + dot4(xb[k],   wb);
      a1 += dot4(xa[k+1], wa) + dot4(xb[k+1], wb);
    }
    float Ac = As[co], Sc = Ss[co];
    float y = fmaxf(fmaxf(a0*Ac+Sc, a1*Ac+Sc), 0.f);
    out[((b*128 + co)<<10) + tc*128 + p] = f2bf(y);
  }
}

// ---------------- conv2 (k=5,pad2) + BN2 + ReLU + maxpool2 ----------------
// in: [128][128][1024] bf16 -> seq: [512][128][256] bf16 (layout [t'][b][co])
__global__ __launch_bounds__(256) void k_conv2(
    const u16* __restrict__ cin, const float* __restrict__ w,
    const float* __restrict__ cb, const float* __restrict__ bg, const float* __restrict__ bb,
    const float* __restrict__ bm, const float* __restrict__ bv, u16* __restrict__ seq)
{
  __shared__ __align__(16) float xs[16*132];
  __shared__ __align__(16) float wl[64*16*8];   // [c][ci][k(pad8)]
  __shared__ float As[64], Ss[64];
  const int tid = threadIdx.x;
  const int tc  = blockIdx.x;    // 0..7  (64 pooled t' per chunk)
  const int cog = blockIdx.y;    // 0..3  (64 co per group)
  const int b   = blockIdx.z;
  const int co0 = cog*64;
  const int tau0 = tc*128;
  if(tid < 64){
    int co = co0 + tid;
    float a = bg[co] * rsqrtf(bv[co] + 1e-5f);
    As[tid] = a; Ss[tid] = (cb[co] - bm[co])*a + bb[co];
  }
  const int q  = tid & 15;       // t' group of 4
  const int cg = tid >> 4;       // co group of 4
  float acc[4][4][2];
  #pragma unroll
  for(int c=0;c<4;c++)
    #pragma unroll
    for(int tl=0;tl<4;tl++){ acc[c][tl][0]=0.f; acc[c][tl][1]=0.f; }
  for(int ci0 = 0; ci0 < 128; ci0 += 16){
    __syncthreads();
    for(int f = tid; f < 16*132; f += 256){
      int ci = f / 132, tt = f - ci*132;
      int tg = tau0 + tt - 2;
      float val = 0.f;
      if(tg >= 0 && tg < 1024) val = b2f(cin[((b*128 + ci0+ci)<<10) + tg]);
      xs[f] = val;
    }
    for(int f = tid; f < 64*16*5; f += 256){
      int c = f / 80; int r = f - c*80; int ci = r/5; int k = r - ci*5;
      wl[(c*16+ci)*8 + k] = w[((co0+c)*128 + ci0+ci)*5 + k];
    }
    __syncthreads();
    #pragma unroll 4
    for(int ci = 0; ci < 16; ci++){
      const float4* xr = (const float4*)&xs[ci*132 + 8*q];
      float4 x0 = xr[0], x1 = xr[1], x2 = xr[2];
      float xv[12];
      xv[0]=x0.x; xv[1]=x0.y; xv[2]=x0.z; xv[3]=x0.w;
      xv[4]=x1.x; xv[5]=x1.y; xv[6]=x1.z; xv[7]=x1.w;
      xv[8]=x2.x; xv[9]=x2.y; xv[10]=x2.z; xv[11]=x2.w;
      #pragma unroll
      for(int c=0;c<4;c++){
        const float* wp = &wl[((cg*4+c)*16 + ci)*8];
        float w0=wp[0], w1=wp[1], w2=wp[2], w3=wp[3], w4=wp[4];
        #pragma unroll
        for(int tl=0; tl<4; tl++){
          acc[c][tl][0] += xv[2*tl+0]*w0 + xv[2*tl+1]*w1 + xv[2*tl+2]*w2 + xv[2*tl+3]*w3 + xv[2*tl+4]*w4;
          acc[c][tl][1] += xv[2*tl+1]*w0 + xv[2*tl+2]*w1 + xv[2*tl+3]*w2 + xv[2*tl+4]*w3 + xv[2*tl+5]*w4;
        }
      }
    }
  }
  #pragma unroll
  for(int c=0;c<4;c++){
    float Ac = As[cg*4+c], Sc = Ss[cg*4+c];
    #pragma unroll
    for(int tl=0;tl<4;tl++){
      float y0 = acc[c][tl][0]*Ac + Sc;
      float y1 = acc[c][tl][1]*Ac + Sc;
      float y  = fmaxf(fmaxf(y0, y1), 0.f);
      int tp = tc*64 + q*4 + tl;
      seq[(tp*128 + b)*256 + co0 + cg*4 + c] = f2bf(y);
    }
  }
}

// ---------------- xp = LN(seq @ wih.T + bih)  via split-precision bf16 MFMA --
// seq: [65536 rows][256] bf16 (exact) ; wih: [384][256] f32 -> xp bf16.
// W split as W_hi + W_lo (both bf16): A*W_hi + A*W_lo in f32 accumulators
// recovers ~17 mantissa bits of W -> f32-equivalent accuracy.
// Block: 128 rows, 8 waves, 24 col-tiles, K=8x32; 48 MFMA/K-step.
__global__ __launch_bounds__(512) void k_xp(
    const u16* __restrict__ seq,
    const float* __restrict__ fw, const float* __restrict__ fbi, const float* __restrict__ fg, const float* __restrict__ fb,
    const float* __restrict__ bw, const float* __restrict__ bbi, const float* __restrict__ bg_, const float* __restrict__ bb_,
    u16* __restrict__ xpf, u16* __restrict__ xpb)
{
  // LDS: staging { wb_hi [384][40] @0 (30720B), wb_lo @30720 (30720B) }
  //      overlaid by outstage [128][392] bf16 (100352B) in epilogue;
  //      LN params at 100352 (4608B). Total 104960B.
  __shared__ __align__(16) char lds[104960];
  u16*   wbh  = (u16*)lds;                       // W_hi [384][40] bf16
  u16*   wbl  = (u16*)(lds + 30720);             // W_lo [384][40] bf16
  u16*   ost  = (u16*)lds;                       // outstage [128][392] bf16
  float* lnbi = (float*)(lds + 100352);
  float* lng  = lnbi + 384;
  float* lnb2 = lnbi + 768;
  const float *W, *BI, *LG, *LB; u16* out;
  if(blockIdx.y == 0){ W=fw; BI=fbi; LG=fg;  LB=fb;  out=xpf; }
  else               { W=bw; BI=bbi; LG=bg_; LB=bb_; out=xpb; }
  const int tid = threadIdx.x;
  const int row0 = blockIdx.x * 128;
  const int w = tid >> 6;        // wave -> 16-row tile
  const int l = tid & 63;
  const int g = l >> 4;          // k-group 0..3
  const int c = l & 15;          // col-within-tile / row-within-tile
  if(tid < 384){ lnbi[tid] = BI[tid]; lng[tid] = LG[tid]; lnb2[tid] = LB[tid]; }
  // prefetch all A fragments: row = row0 + w*16 + c, 8 k-steps x 8 bf16
  const int arow = row0 + w*16 + c;
  bf16x8 afr[8];
  #pragma unroll
  for(int ks=0; ks<8; ks++)
    afr[ks] = *(const bf16x8*)&seq[arow*256 + ks*32 + g*8];
  f32x4 acc[24];
  #pragma unroll
  for(int n=0; n<24; n++) acc[n] = (f32x4){0.f,0.f,0.f,0.f};
  #pragma unroll
  for(int ks=0; ks<8; ks++){
    __syncthreads();
    // stage W[:, ks*32 .. +31] as hi/lo bf16, pitch 40
    for(int f = tid; f < 12288; f += 512){
      int jj = f >> 5, kk = f & 31;
      float wv = W[jj*256 + ks*32 + kk];
      u16 hi = f2bf(wv);
      wbh[jj*40 + kk] = hi;
      wbl[jj*40 + kk] = f2bf(wv - b2f(hi));
    }
    __syncthreads();
    #pragma unroll
    for(int n=0; n<24; n++){
      bf16x8 bhi = *(const bf16x8*)&wbh[(n*16 + c)*40 + g*8];
      bf16x8 blo = *(const bf16x8*)&wbl[(n*16 + c)*40 + g*8];
      acc[n] = __builtin_amdgcn_mfma_f32_16x16x32_bf16(afr[ks], bhi, acc[n], 0, 0, 0);
      acc[n] = __builtin_amdgcn_mfma_f32_16x16x32_bf16(afr[ks], blo, acc[n], 0, 0, 0);
    }
  }
  __syncthreads();   // W staging dead; begin epilogue
  // bias
  float bic[24];
  #pragma unroll
  for(int n=0; n<24; n++) bic[n] = lnbi[n*16 + c];
  // LN stats per row (row = w*16 + g*4 + q); row data spread over 16 lanes (c)
  float mean[4], rs[4];
  #pragma unroll
  for(int q=0; q<4; q++){
    float s = 0.f, ss = 0.f;
    #pragma unroll
    for(int n=0; n<24; n++){
      float u = acc[n][q] + bic[n];
      s += u; ss += u*u;
    }
    #pragma unroll
    for(int msk=1; msk<16; msk<<=1){ s += __shfl_xor(s,msk); ss += __shfl_xor(ss,msk); }
    mean[q] = s * (1.f/384.f);
    float var = fmaxf(ss * (1.f/384.f) - mean[q]*mean[q], 0.f);
    rs[q] = rsqrtf(var + 1e-5f);
  }
  #pragma unroll
  for(int n=0; n<24; n++){
    float lgv = lng[n*16 + c], lbv = lnb2[n*16 + c];
    #pragma unroll
    for(int q=0; q<4; q++){
      float u = acc[n][q] + bic[n];
      float y = (u - mean[q])*rs[q]*lgv + lbv;
      ost[(w*16 + g*4 + q)*392 + n*16 + c] = f2bf(y);
    }
  }
  __syncthreads();
  // coalesced copy: 128 rows x 48 uint4
  for(int f = tid; f < 6144; f += 512){
    int row = f / 48, ch = f - row*48;
    uint4 v = *(const uint4*)&ost[row*392 + ch*8];
    *(uint4*)&out[(row0 + row)*384 + ch*8] = v;
  }
}

// ---------------- LayerNorm-LSTM scan (one block per (batch,dir)) ----------------
// Quad-permuted rows (r=(j&3)*96+(j>>2)): gate exchange is 3 shfl_xor.
// xt staged 8 steps at a time through an LDS double-buffer, so 7 of 8 steps
// have NO global ops in flight at barriers (no vmcnt drain exposure).
__global__ __launch_bounds__(384, 1) void k_lstm(
    const u16* __restrict__ xpf, const u16* __restrict__ xpb,
    const float* __restrict__ fwhh, const float* __restrict__ fbhh, const float* __restrict__ fgh, const float* __restrict__ fbh2,
    const float* __restrict__ fgho, const float* __restrict__ fbho,
    const float* __restrict__ bwhh, const float* __restrict__ bbhh, const float* __restrict__ bgh, const float* __restrict__ bbh2,
    const float* __restrict__ bgho, const float* __restrict__ bbho,
    u16* __restrict__ hcat)
{
  __shared__ __align__(16) float hx[96];       // h state, f32
  __shared__ __align__(16) float2 red1[8];     // LN1 wave partials (6 used)
  __shared__ __align__(16) float2 red2[8];     // LN2 wave partials (6 used)
  __shared__ __align__(16) u16 hstage[16][96]; // hcat staging (16 steps)
  __shared__ __align__(16) u16 xstage[2][8][384]; // xt staging (2 groups of 8 steps)
  const int b   = blockIdx.x;
  const int dir = blockIdx.y;
  const u16* xp;
  const float *whh, *bh, *gh, *bh2, *gho, *bho;
  if(dir == 0){ xp=xpf; whh=fwhh; bh=fbhh; gh=fgh; bh2=fbh2; gho=fgho; bho=fbho; }
  else        { xp=xpb; whh=bwhh; bh=bbhh; gh=bgh; bh2=bbh2; gho=bgho; bho=bbho; }
  const int j    = threadIdx.x;
  const int wid  = j >> 6;
  const int lane = j & 63;
  const int q    = j & 3;        // gate index (0=i,1=f,2=g,3=o)
  const int m    = j >> 2;       // hidden index 0..95
  const int r    = q*96 + m;     // gate row this thread computes
  float wr[96];                  // whh row r in registers
  {
    const float4* wp4 = (const float4*)(whh + r*96);
    #pragma unroll
    for(int kk=0; kk<24; kk++){
      float4 v = wp4[kk];
      wr[4*kk]=v.x; wr[4*kk+1]=v.y; wr[4*kk+2]=v.z; wr[4*kk+3]=v.w;
    }
  }
  const float bh_r = bh[r], gh_r = gh[r], bh2_r = bh2[r];
  const float gho_m = gho[m], bho_m = bho[m];
  float cx = 0.f;
  if(j < 96) hx[j] = 0.f;
  if(j < 2){ red1[6+j] = make_float2(0.f,0.f); red2[6+j] = make_float2(0.f,0.f); }
  const u16* xrow = xp + b*384 + r;              // + ts*49152 per step
  // preload xt for steps 0..7 into buf 0
  {
    #pragma unroll
    for(int k2=0; k2<8; k2++){
      const int tss = dir ? (511 - k2) : k2;
      xstage[0][k2][j] = xrow[tss*49152];
    }
  }
  __syncthreads();
  for(int t=0; t<512; t++){
    const int ts = dir ? (511 - t) : t;
    const int grp = (t>>3) & 1;
    // group-start: prefetch next 8 steps' xt into registers
    u16 pf[8];
    const bool doPf = ((t & 7) == 0) && (t + 8 < 512);
    if(doPf){
      #pragma unroll
      for(int k2=0; k2<8; k2++){
        const int tt = t + 8 + k2;
        const int tss = dir ? (511 - tt) : tt;
        pf[k2] = xrow[tss*49152];
      }
    }
    // xt for this step (LDS, written 8 steps ago)
    const float xt = b2f(xstage[grp][t & 7][j]);
    // ---- phase A: matvec u_r = whh[r,:] . hx ----
    const float4* hp = (const float4*)hx;
    float a0=0.f, a1=0.f, a2=0.f, a3=0.f;
    #pragma unroll
    for(int kk=0; kk<24; kk++){
      float4 h4 = hp[kk];              // broadcast read
      a0 += h4.x * wr[4*kk];
      a1 += h4.y * wr[4*kk+1];
      a2 += h4.z * wr[4*kk+2];
      a3 += h4.w * wr[4*kk+3];
    }
    const float u = (a0+a1)+(a2+a3) + bh_r;
    // ---- LN1 over all 384 rows ----
    float s = u, ss = u*u;
    #pragma unroll
    for(int msk=32; msk; msk>>=1){ s += __shfl_xor(s,msk); ss += __shfl_xor(ss,msk); }
    if(lane == 0) red1[wid] = make_float2(s, ss);
    // stage prefetched xt (vmcnt wait lands here, hidden under matvec+LN1)
    if(doPf){
      #pragma unroll
      for(int k2=0; k2<8; k2++) xstage[grp^1][k2][j] = pf[k2];
    }
    __syncthreads();                             // B1
    float gate;
    {
      const float4* rp = (const float4*)red1;
      float4 p0 = rp[0], p1 = rp[1], p2 = rp[2];
      float S  = (p0.x + p0.z) + (p1.x + p1.z) + (p2.x + p2.z);
      float SS = (p0.y + p0.w) + (p1.y + p1.w) + (p2.y + p2.w);
      const float mean = S*(1.f/384.f);
      const float var  = fmaxf(SS*(1.f/384.f) - mean*mean, 0.f);
      const float rs   = rsqrtf(var + 1e-5f);
      gate = xt + (u - mean)*rs*gh_r + bh2_r;
    }
    // ---- quad exchange: collect i,f,g,o of hidden m onto every lane of quad ----
    const float x1 = __shfl_xor(gate, 1);        // gate index q^1
    const float x2 = __shfl_xor(gate, 2);        // q^2
    const float x3 = __shfl_xor(x1,   2);        // q^3
    const bool qb0 = (q & 1), qb1 = (q & 2);
    const float lo0 = qb0 ? x1 : gate;
    const float lo1 = qb0 ? gate : x1;
    const float hi0 = qb0 ? x3 : x2;
    const float hi1 = qb0 ? x2 : x3;
    const float gi = qb1 ? hi0 : lo0;            // gate 0 (input)
    const float gf = qb1 ? hi1 : lo1;            // gate 1 (forget)
    const float gg = qb1 ? lo0 : hi0;            // gate 2 (cell)
    const float go = qb1 ? lo1 : hi1;            // gate 3 (out)
    // ---- cell update (redundant across the 4 lanes of the quad) ----
    const float cy = sigf(gf)*cx + sigf(gi)*tanh_(gg);
    cx = cy;
    // ---- LN2 over 96 cy: masks >=4 sum the 16 distinct per wave ----
    float s2 = cy, ss2 = cy*cy;
    #pragma unroll
    for(int msk=4; msk<64; msk<<=1){ s2 += __shfl_xor(s2,msk); ss2 += __shfl_xor(ss2,msk); }
    if(lane == 0) red2[wid] = make_float2(s2, ss2);
    __syncthreads();                             // B2
    {
      const float4* rp = (const float4*)red2;
      float4 p0 = rp[0], p1 = rp[1], p2 = rp[2];
      float S2  = (p0.x + p0.z) + (p1.x + p1.z) + (p2.x + p2.z);
      float SS2 = (p0.y + p0.w) + (p1.y + p1.w) + (p2.y + p2.w);
      const float m2  = S2*(1.f/96.f);
      const float v2  = fmaxf(SS2*(1.f/96.f) - m2*m2, 0.f);
      const float rs2 = rsqrtf(v2 + 1e-5f);
      const float lnho = (cy - m2)*rs2*gho_m + bho_m;
      const float hy = sigf(go)*tanh_(lnho);
      if(q == 0){
        hx[m] = hy;
        hstage[t & 15][m] = f2bf(hy);
      }
    }
    __syncthreads();                             // B3 (hx/hstage ready)
    if((t & 15) == 15){
      // flush 16 staged steps: 16 rows x 12 uint4 chunks = 192 workers
      if(j < 192){
        const int row = j / 12, ch = j - row*12;
        const int tbase = t - 15;
        const int tsr = dir ? (511 - (tbase + row)) : (tbase + row);
        uint4 v = *(const uint4*)&hstage[row][ch*8];
        *(uint4*)&hcat[(tsr*128 + b)*192 + dir*96 + ch*8] = v;
      }
    }
  }
}

// ---------------- attention + fc1/BN3/ReLU + fc2 (one block per batch) ----------------
__global__ __launch_bounds__(256) void k_head(
    const u16* __restrict__ hcat, const float* __restrict__ aw,
    const float* __restrict__ f1w, const float* __restrict__ f1b,
    const float* __restrict__ g3, const float* __restrict__ b3, const float* __restrict__ m3, const float* __restrict__ v3,
    const float* __restrict__ fc2w, const float* __restrict__ fc2bias,
    float* __restrict__ out)
{
  __shared__ float p[512];
  __shared__ float red[8];
  __shared__ __align__(16) float ctx[192];
  __shared__ float h2[256];
  __shared__ float awl[192];
  const int b = blockIdx.x;
  const int tid = threadIdx.x;
  if(tid < 192) awl[tid] = aw[tid];
  __syncthreads();
  float sc0 = 0.f, sc1 = 0.f;
  #pragma unroll
  for(int i=0;i<2;i++){
    int t = i*256 + tid;
    const uint4* hp = (const uint4*)(hcat + (t*128 + b)*192);
    float acc = 0.f;
    #pragma unroll 6
    for(int qq=0;qq<24;qq++){
      uint4 pv = hp[qq];
      acc += b2f((u16)(pv.x&0xffffu))*awl[qq*8+0] + b2f((u16)(pv.x>>16))*awl[qq*8+1]
           + b2f((u16)(pv.y&0xffffu))*awl[qq*8+2] + b2f((u16)(pv.y>>16))*awl[qq*8+3]
           + b2f((u16)(pv.z&0xffffu))*awl[qq*8+4] + b2f((u16)(pv.z>>16))*awl[qq*8+5]
           + b2f((u16)(pv.w&0xffffu))*awl[qq*8+6] + b2f((u16)(pv.w>>16))*awl[qq*8+7];
    }
    if(i==0) sc0 = acc; else sc1 = acc;
  }
  float mx = fmaxf(sc0, sc1);
  for(int msk=32; msk; msk>>=1) mx = fmaxf(mx, __shfl_xor(mx,msk));
  if((tid&63)==0) red[tid>>6] = mx;
  __syncthreads();
  mx = fmaxf(fmaxf(red[0],red[1]), fmaxf(red[2],red[3]));
  float e0 = __expf(sc0-mx), e1 = __expf(sc1-mx);
  float sm = e0 + e1;
  for(int msk=32; msk; msk>>=1) sm += __shfl_xor(sm,msk);
  if((tid&63)==0) red[4 + (tid>>6)] = sm;
  __syncthreads();
  const float inv = 1.f/(red[4]+red[5]+red[6]+red[7]);
  p[tid] = e0*inv; p[tid+256] = e1*inv;
  __syncthreads();
  if(tid < 192){
    float acc = 0.f;
    for(int t=0;t<512;t++){
      acc += p[t] * b2f(hcat[(t*128 + b)*192 + tid]);
    }
    ctx[tid] = acc;
  }
  __syncthreads();
  {
    const float4* cv = (const float4*)ctx;
    const float4* wp = (const float4*)(f1w + tid*192);
    float acc = 0.f;
    #pragma unroll 8
    for(int qq=0;qq<48;qq++){
      acc += dot4(wp[qq], cv[qq]);
    }
    acc += f1b[tid];
    float a = g3[tid] * rsqrtf(v3[tid] + 1e-5f);
    float y = (acc - m3[tid])*a + b3[tid];
    h2[tid] = fmaxf(y, 0.f);
  }
  __syncthreads();
  if(tid < 6){
    float acc = fc2bias[tid];
    for(int k=0;k<256;k++) acc += h2[k]*fc2w[tid*256 + k];
    out[b*6 + tid] = acc;
  }
}

extern "C" void kernel_launch(void* const* d_in, const int* in_sizes, int n_in,
                              void* d_out, int out_size, void* d_ws, size_t ws_size,
                              hipStream_t stream)
{
  (void)in_sizes; (void)n_in; (void)out_size; (void)ws_size;
  const float* X      = (const float*)d_in[0];
  const float* c1w    = (const float*)d_in[1];
  const float* c1b    = (const float*)d_in[2];
  const float* bn1g   = (const float*)d_in[3];
  const float* bn1b   = (const float*)d_in[4];
  const float* bn1m   = (const float*)d_in[5];
  const float* bn1v   = (const float*)d_in[6];
  const float* c2w    = (const float*)d_in[7];
  const float* c2b    = (const float*)d_in[8];
  const float* bn2g   = (const float*)d_in[9];
  const float* bn2b   = (const float*)d_in[10];
  const float* bn2m   = (const float*)d_in[11];
  const float* bn2v   = (const float*)d_in[12];
  const float* fwih   = (const float*)d_in[13];
  const float* fbih   = (const float*)d_in[14];
  const float* fwhh   = (const float*)d_in[15];
  const float* fbhh   = (const float*)d_in[16];
  const float* flnihg = (const float*)d_in[17];
  const float* flnihb = (const float*)d_in[18];
  const float* flnhhg = (const float*)d_in[19];
  const float* flnhhb = (const float*)d_in[20];
  const float* flnhog = (const float*)d_in[21];
  const float* flnhob = (const float*)d_in[22];
  const float* bwih   = (const float*)d_in[23];
  const float* bbih   = (const float*)d_in[24];
  const float* bwhh   = (const float*)d_in[25];
  const float* bbhh   = (const float*)d_in[26];
  const float* blnihg = (const float*)d_in[27];
  const float* blnihb = (const float*)d_in[28];
  const float* blnhhg = (const float*)d_in[29];
  const float* blnhhb = (const float*)d_in[30];
  const float* blnhog = (const float*)d_in[31];
  const float* blnhob = (const float*)d_in[32];
  const float* attnw  = (const float*)d_in[33];
  const float* fc1w   = (const float*)d_in[34];
  const float* fc1b   = (const float*)d_in[35];
  const float* bn3g   = (const float*)d_in[36];
  const float* bn3b   = (const float*)d_in[37];
  const float* bn3m   = (const float*)d_in[38];
  const float* bn3v   = (const float*)d_in[39];
  const float* fc2w   = (const float*)d_in[40];
  const float* fc2b_  = (const float*)d_in[41];

  // Workspace layout (peak 128 MiB), liveness-based overlays:
  //   seq  @   0 .. 32M   (conv2 out; dead after k_xp)
  //   xpf  @  32M .. 80M
  //   xpb  @  80M ..128M
  //   c1o  @  96M ..128M  (conv1 out; dead after conv2)   [xpb written after c1o is dead]
  //   hcat @   0 .. 24M   (lstm out; overlays dead seq)
  char* ws = (char*)d_ws;
  const size_t MB = 1048576;
  u16* seq  = (u16*)(ws);
  u16* xpf  = (u16*)(ws + 32*MB);
  u16* xpb  = (u16*)(ws + 80*MB);
  u16* c1o  = (u16*)(ws + 96*MB);
  u16* hcat = (u16*)(ws);

  k_conv1<<<dim3(8,128),  256, 0, stream>>>(X,   c1w, c1b, bn1g, bn1b, bn1m, bn1v, c1o);
  k_conv2<<<dim3(8,4,128),256, 0, stream>>>(c1o, c2w, c2b, bn2g, bn2b, bn2m, bn2v, seq);
  k_xp  <<<dim3(512,2),   512, 0, stream>>>(seq, fwih, fbih, flnihg, flnihb,
                                                 bwih, bbih, blnihg, blnihb, xpf, xpb);
  k_lstm<<<dim3(128,2),   384, 0, stream>>>(xpf, xpb,
      fwhh, fbhh, flnhhg, flnhhb, flnhog, flnhob,
      bwhh, bbhh, blnhhg, blnhhb, blnhog, blnhob, hcat);
  k_head<<<dim3(128),     256, 0, stream>>>(hcat, attnw, fc1w, fc1b,
      bn3g, bn3b, bn3m, bn3v, fc2w, fc2b_, (float*)d_out);
}